// Round 2
// baseline (711.914 us; speedup 1.0000x reference)
//
#include <hip/hip_runtime.h>
#include <math.h>

#define Bc   2
#define Hc   240
#define Wc   1216
#define CHG  64
#define HWc  (Hc*Wc)          // 291840
#define NPIX (Bc*HWc)         // 583680

// d_out layout (floats): [feat 583680][offset 2*18*HW][aff 2*9*HW]
#define OUT1 (NPIX)
#define OUT2 (OUT1 + Bc*18*HWc)

// zero-padded bilinear sample from a (Hc,Wc) plane
__device__ __forceinline__ float bilin(const float* __restrict__ f, float ys, float xs) {
    float y0f = floorf(ys), x0f = floorf(xs);
    float wy1 = ys - y0f,   wx1 = xs - x0f;
    float wy0 = 1.f - wy1,  wx0 = 1.f - wx1;
    int y0 = (int)y0f, x0 = (int)x0f;
    int y1 = y0 + 1,   x1 = x0 + 1;
    int y0c = min(max(y0, 0), Hc-1), y1c = min(max(y1, 0), Hc-1);
    int x0c = min(max(x0, 0), Wc-1), x1c = min(max(x1, 0), Wc-1);
    float my0 = (y0 >= 0 && y0 < Hc) ? 1.f : 0.f;
    float my1 = (y1 >= 0 && y1 < Hc) ? 1.f : 0.f;
    float mx0 = (x0 >= 0 && x0 < Wc) ? 1.f : 0.f;
    float mx1 = (x1 >= 0 && x1 < Wc) ? 1.f : 0.f;
    float v00 = f[y0c*Wc + x0c] * (my0*mx0);
    float v01 = f[y0c*Wc + x1c] * (my0*mx1);
    float v10 = f[y1c*Wc + x0c] * (my1*mx0);
    float v11 = f[y1c*Wc + x1c] * (my1*mx1);
    return wy0*(wx0*v00 + wx1*v01) + wy1*(wx0*v10 + wx1*v11);
}

// reorder w_oa (24,64,3,3) -> wr[(c*9+j)*24 + oc]
__global__ void reorder_w(const float* __restrict__ w_oa, float* __restrict__ wr) {
    int i = blockIdx.x*256 + threadIdx.x;   // over 24*576
    if (i < 24*576) {
        int oc = i / 576; int cj = i - oc*576;
        wr[cj*24 + oc] = w_oa[i];
    }
}

// fused: 3x3 conv (64->24) + offset/aff epilogue + init masked feat buffer
__global__ __launch_bounds__(256) void conv_epilogue(
    const float* __restrict__ guid, const float* __restrict__ conf,
    const float* __restrict__ wr,   const float* __restrict__ b_oa,
    const float* __restrict__ aff_scale,
    const float* __restrict__ feat_init, const float* __restrict__ feat_fix,
    float* __restrict__ dout, float* __restrict__ buf0)
{
    int p  = blockIdx.x*256 + threadIdx.x;
    int b  = p / HWc;
    int hw = p - b*HWc;
    int h  = hw / Wc;
    int w  = hw - h*Wc;

    // clipped 3x3 neighborhood offsets + masks (zero padding)
    int   aoff[9];
    float msk[9];
    #pragma unroll
    for (int dy = 0; dy < 3; ++dy) {
        int hy = h + dy - 1;
        float my = (hy >= 0 && hy < Hc) ? 1.f : 0.f;
        int hyc = min(max(hy, 0), Hc-1);
        #pragma unroll
        for (int dx = 0; dx < 3; ++dx) {
            int wx = w + dx - 1;
            float mx = (wx >= 0 && wx < Wc) ? 1.f : 0.f;
            int wxc = min(max(wx, 0), Wc-1);
            aoff[dy*3+dx] = hyc*Wc + wxc;
            msk [dy*3+dx] = my*mx;
        }
    }

    float acc[24];
    #pragma unroll
    for (int oc = 0; oc < 24; ++oc) acc[oc] = b_oa[oc];

    const float* gb = guid + b*CHG*HWc;
    for (int c = 0; c < CHG; ++c) {
        const float* gc = gb + c*HWc;
        #pragma unroll
        for (int j = 0; j < 9; ++j) {
            float g = gc[aoff[j]] * msk[j];
            const float* wp = wr + (c*9 + j)*24;   // wave-uniform address -> s_load
            #pragma unroll
            for (int oc = 0; oc < 24; ++oc)
                acc[oc] = fmaf(g, wp[oc], acc[oc]);
        }
    }

    // epilogue
    // offset = concat([o1,o2],ch).reshape(B,8,2,H,W): tap k -> (acc[2k], acc[2k+1])
    float scale = 1.f / (aff_scale[0] + 1e-8f);
    const float* cb = conf + b*HWc;
    float oyv[8], oxv[8], af[8];
    float ssum = 0.f;
    #pragma unroll
    for (int k = 0; k < 8; ++k) { oyv[k] = acc[2*k]; oxv[k] = acc[2*k+1]; }
    #pragma unroll
    for (int k = 0; k < 8; ++k) {
        float a  = tanhf(acc[16+k]) * scale;
        float ys = (float)h + oyv[k];
        float xs = (float)w + oxv[k];
        float ca = bilin(cb, ys, xs);
        a *= ca;
        af[k] = a;
        ssum += fabsf(a);
    }
    float inv = 1.f / fmaxf(ssum + 1e-4f, 1.f);
    float asum = 0.f;
    #pragma unroll
    for (int k = 0; k < 8; ++k) { af[k] *= inv; asum += af[k]; }
    float aref = 1.f - asum;

    float* ob = dout + OUT1 + b*18*HWc + hw;
    float* ab = dout + OUT2 + b*9*HWc  + hw;
    #pragma unroll
    for (int kf = 0; kf < 9; ++kf) {
        float oy, ox, av;
        if (kf == 4) { oy = 0.f; ox = 0.f; av = aref; }
        else { int k = (kf < 4) ? kf : kf-1; oy = oyv[k]; ox = oxv[k]; av = af[k]; }
        ob[(2*kf  )*HWc] = oy;
        ob[(2*kf+1)*HWc] = ox;
        ab[kf*HWc]       = av;
    }

    float ff = feat_fix[p];
    buf0[p] = (ff > 0.f) ? ff : feat_init[p];
}

// one propagation step: 9-tap deformable bilinear gather + weighted sum
__global__ __launch_bounds__(256) void prop_step(
    const float* __restrict__ fin,
    const float* __restrict__ doff,   // d_out offset section
    const float* __restrict__ daff,   // d_out aff section
    const float* __restrict__ feat_fix,
    float* __restrict__ out, int apply_mask)
{
    int p  = blockIdx.x*256 + threadIdx.x;
    int b  = p / HWc;
    int hw = p - b*HWc;
    int h  = hw / Wc;
    int w  = hw - h*Wc;

    const float* fb = fin  + b*HWc;
    const float* ob = doff + b*18*HWc + hw;
    const float* ab = daff + b*9*HWc  + hw;

    float s = 0.f;
    #pragma unroll
    for (int kf = 0; kf < 9; ++kf) {
        float offy = ob[(2*kf  )*HWc];
        float offx = ob[(2*kf+1)*HWc];
        float a    = ab[kf*HWc];
        float ys = (float)(h + kf/3 - 1) + offy;
        float xs = (float)(w + kf%3 - 1) + offx;
        s += a * bilin(fb, ys, xs);
    }
    if (apply_mask) {
        float ff = feat_fix[p];
        out[p] = (ff > 0.f) ? ff : s;
    } else {
        out[p] = s;
    }
}

extern "C" void kernel_launch(void* const* d_in, const int* in_sizes, int n_in,
                              void* d_out, int out_size, void* d_ws, size_t ws_size,
                              hipStream_t stream) {
    const float* feat_init  = (const float*)d_in[0];
    const float* guidance   = (const float*)d_in[1];
    const float* confidence = (const float*)d_in[2];
    const float* feat_fix   = (const float*)d_in[3];
    const float* w_oa       = (const float*)d_in[4];
    const float* b_oa       = (const float*)d_in[5];
    const float* aff_scale  = (const float*)d_in[6];
    float* out = (float*)d_out;

    float* wr   = (float*)d_ws;          // 13824 floats
    float* buf0 = wr + 24*576;           // NPIX floats
    float* buf1 = buf0 + NPIX;           // NPIX floats

    reorder_w<<<(24*576 + 255)/256, 256, 0, stream>>>(w_oa, wr);
    conv_epilogue<<<NPIX/256, 256, 0, stream>>>(
        guidance, confidence, wr, b_oa, aff_scale, feat_init, feat_fix, out, buf0);

    float* doff = out + OUT1;
    float* daff = out + OUT2;
    float* bufs[2] = {buf0, buf1};
    for (int i = 1; i <= 18; ++i) {
        const float* fi = bufs[(i-1) & 1];
        float* fo = (i == 18) ? out : bufs[i & 1];
        prop_step<<<NPIX/256, 256, 0, stream>>>(fi, doff, daff, feat_fix, fo, (i < 18) ? 1 : 0);
    }
}